// Round 20
// baseline (97.394 us; speedup 1.0000x reference)
//
#include <hip/hip_runtime.h>
#include <math.h>

#define N_DIM 64
#define C_DIM 512
#define K_DIM 64
#define P_DIM 900
#define P_PAD 928          // a2 padded pixels (29*32)
#define PTILES 15          // 64-px tiles

typedef __attribute__((ext_vector_type(8))) short short8;   // 8 bf16 = 4 VGPR
typedef __attribute__((ext_vector_type(4))) float f32x4;
typedef __attribute__((ext_vector_type(4))) uint  u32x4;

#define A2_ELEMS   ((size_t)N_DIM * K_DIM * P_PAD)
#define ASUM_ELEMS ((size_t)N_DIM * K_DIM * PTILES)
#define SSQ_ELEMS  ((size_t)8 * N_DIM * P_DIM)
#define XTF_ELEMS  ((size_t)N_DIM * PTILES * 16 * 4 * 512)   // 63 MB bf16

// fp32 -> bf16 bits, round-to-nearest-even (inputs finite)
__device__ inline ushort f2bf(float f) {
  uint u = __builtin_bit_cast(uint, f);
  u += 0x7FFFu + ((u >> 16) & 1u);
  return (ushort)(u >> 16);
}
__device__ inline uint pk2(float a, float b) {
  return (uint)f2bf(a) | ((uint)f2bf(b) << 16);
}
__device__ __forceinline__ void gload16(const float* g, float* lds_base) {
  __builtin_amdgcn_global_load_lds(
      (const __attribute__((address_space(1))) void*)g,
      (__attribute__((address_space(3))) void*)lds_base, 16, 0, 0);
}

// ---------------------------------------------------------------------------
// Kernel T (v2): DRAM-ROW-FRIENDLY transpose. Block (ct, n) owns 64 c-rows
// and reads each 3600-B row CONTIGUOUSLY (4 sequential 1-KB gload16) --
// fixes the 256-B-run row-activation wall (rounds 12-19: 1.3-1.8 TB/s).
// LDS tile [8 c][1024 px] fp32, double-buffered (64 KB), 8 iters.
// Emits xtf bf16 in assign-fragment order: panel[(n*15+pt)*16+ks)*4+lhi]
// = [64 px][8 c], 1-KB contiguous writes; px>=900 zeroed.
// ssq accumulated in registers across iters (px->thread map fixed).
// ---------------------------------------------------------------------------
__global__ __launch_bounds__(256, 2) void transpose_x(
    const float* __restrict__ x, ushort* __restrict__ xtf,
    float* __restrict__ ssq_part)
{
  const int ct = blockIdx.x, n = blockIdx.y, c0 = ct * 64;
  const int tid = threadIdx.x, wv = tid >> 6, lane = tid & 63;

  __shared__ float xs[2][8192];       // [8 c][1024 px] x 2

  const float* xb = x + (size_t)n * C_DIM * P_DIM;
  // per-lane source px for staging (clamped to last 16B of the row)
  // load j (j = wv*8+i): r = j>>2 (c-row 0..7), q = j&3 (px quarter)
#define STAGE(b, it)                                                           \
  {                                                                            \
    _Pragma("unroll")                                                          \
    for (int i = 0; i < 8; ++i) {                                              \
      int j = wv * 8 + i;                                                      \
      int r = j >> 2, q = j & 3;                                               \
      int px = q * 256 + lane * 4;                                             \
      if (px > 896) px = 896;                                                  \
      gload16(xb + (size_t)(c0 + (it) * 8 + r) * P_DIM + px,                   \
              &xs[b][r * 1024 + q * 256]);                                     \
    }                                                                          \
  }

  float ssq_acc[4] = {0.f, 0.f, 0.f, 0.f};

  STAGE(0, 0);
#pragma unroll
  for (int it = 0; it < 8; ++it) {
    if (it + 1 < 8) STAGE((it + 1) & 1, it + 1);
    if (it + 1 < 8) asm volatile("s_waitcnt vmcnt(8)" ::: "memory");
    else            asm volatile("s_waitcnt vmcnt(0)" ::: "memory");
    __builtin_amdgcn_sched_barrier(0);
    __builtin_amdgcn_s_barrier();       // tile it ready

    const float* buf = xs[it & 1];
    const int cg = c0 + it * 8;          // this iter's c-octet
    const int ks = cg >> 5, lhi = (cg >> 3) & 3;
    ushort* dst_base = xtf + (((size_t)(n * PTILES) * 16 + ks) * 4 + lhi) * 512;
#pragma unroll
    for (int pass = 0; pass < 4; ++pass) {
      int px = pass * 256 + tid;         // 0..1023
      float v[8];
#pragma unroll
      for (int c = 0; c < 8; ++c) v[c] = buf[c * 1024 + px];
      if (px >= P_DIM) {
#pragma unroll
        for (int c = 0; c < 8; ++c) v[c] = 0.f;
      }
      float s = 0.f;
#pragma unroll
      for (int c = 0; c < 8; ++c) s += v[c] * v[c];
      ssq_acc[pass] += s;
      if (px < PTILES * 64) {            // px < 960
        int pt = px >> 6, pxl = px & 63;
        u32x4 wvr;
        wvr[0] = pk2(v[0], v[1]); wvr[1] = pk2(v[2], v[3]);
        wvr[2] = pk2(v[4], v[5]); wvr[3] = pk2(v[6], v[7]);
        *(u32x4*)(dst_base + (size_t)pt * 16 * 4 * 512 + pxl * 8) = wvr;
      }
    }
    __builtin_amdgcn_s_barrier();       // reads done before buf reuse
  }
#undef STAGE

  // per-px ssq partial for this ctile (px->thread map fixed across iters)
#pragma unroll
  for (int pass = 0; pass < 4; ++pass) {
    int px = pass * 256 + tid;
    if (px < P_DIM)
      ssq_part[((size_t)ct * N_DIM + n) * P_DIM + px] = ssq_acc[pass];
  }
}

// ---------------------------------------------------------------------------
// Kernel A (v12): logits GEMM from xtf (L3-hot, fragment-ordered) + softmax.
// Inner loop = short8 load + MFMA only. invn from ssq_part.
// ks loop fully unrolled (rule #20: wfrag runtime index -> scratch).
// ---------------------------------------------------------------------------
__global__ __launch_bounds__(256, 2) void netvlad_assign(
    const float* __restrict__ w, const ushort* __restrict__ xtf,
    const float* __restrict__ ssq_part,
    ushort* __restrict__ a2, float* __restrict__ asum_part)
{
  const int n = blockIdx.y, bpt = blockIdx.x, p0 = bpt * 64;
  const int tid = threadIdx.x, wave = tid >> 6, lane = tid & 63;
  const int l15 = lane & 15, lhi = lane >> 4;

  __shared__ float invn_s[64];
  __shared__ float wredm[4][4][16];
  __shared__ float wreds[4][4][16];

  short8 wfrag[16];
  const float* wrow = w + (size_t)(wave * 16 + l15) * C_DIM + lhi * 8;
#pragma unroll
  for (int ks = 0; ks < 16; ++ks) {
    f32x4 f0 = *(const f32x4*)(wrow + ks * 32);
    f32x4 f1 = *(const f32x4*)(wrow + ks * 32 + 4);
    u32x4 up;
    up[0] = pk2(f0[0], f0[1]); up[1] = pk2(f0[2], f0[3]);
    up[2] = pk2(f1[0], f1[1]); up[3] = pk2(f1[2], f1[3]);
    wfrag[ks] = __builtin_bit_cast(short8, up);
  }

  if (tid < 64) {
    int p = p0 + tid;
    float s = 0.f;
    if (p < P_DIM) {
#pragma unroll
      for (int ct = 0; ct < 8; ++ct)
        s += ssq_part[((size_t)ct * N_DIM + n) * P_DIM + p];
    }
    invn_s[tid] = 1.0f / fmaxf(sqrtf(s), 1e-12f);
  }

  const ushort* xf_base = xtf + ((size_t)(n * PTILES + bpt) * 16) * 4 * 512;
  f32x4 acc[4];
#pragma unroll
  for (int pt = 0; pt < 4; ++pt) acc[pt] = (f32x4){0.f, 0.f, 0.f, 0.f};

#pragma unroll
  for (int ks = 0; ks < 16; ++ks) {
#pragma unroll
    for (int pt = 0; pt < 4; ++pt) {
      short8 xf = *(const short8*)(xf_base + ((size_t)ks * 4 + lhi) * 512
                                          + (pt * 16 + l15) * 8);
      acc[pt] = __builtin_amdgcn_mfma_f32_16x16x32_bf16(wfrag[ks], xf, acc[pt], 0, 0, 0);
    }
  }
  __syncthreads();   // invn_s ready

  float linv[4], lg[4][4];
#pragma unroll
  for (int pt = 0; pt < 4; ++pt) {
    linv[pt] = invn_s[pt * 16 + l15];
    float m = -1e30f;
#pragma unroll
    for (int r = 0; r < 4; ++r) { lg[pt][r] = acc[pt][r] * linv[pt]; m = fmaxf(m, lg[pt][r]); }
    m = fmaxf(m, __shfl_xor(m, 16));
    m = fmaxf(m, __shfl_xor(m, 32));
    if (lhi == 0) wredm[wave][pt][l15] = m;
  }
  __syncthreads();
#pragma unroll
  for (int pt = 0; pt < 4; ++pt) {
    float m = fmaxf(fmaxf(wredm[0][pt][l15], wredm[1][pt][l15]),
                    fmaxf(wredm[2][pt][l15], wredm[3][pt][l15]));
    float s = 0.f;
#pragma unroll
    for (int r = 0; r < 4; ++r) { lg[pt][r] = __expf(lg[pt][r] - m); s += lg[pt][r]; }
    s += __shfl_xor(s, 16);
    s += __shfl_xor(s, 32);
    if (lhi == 0) wreds[wave][pt][l15] = s;
  }
  __syncthreads();

  ushort* a2b = a2 + (size_t)n * K_DIM * P_PAD;
  float asr[4] = {0.f, 0.f, 0.f, 0.f};
#pragma unroll
  for (int pt = 0; pt < 4; ++pt) {
    float stot = wreds[0][pt][l15] + wreds[1][pt][l15] +
                 wreds[2][pt][l15] + wreds[3][pt][l15];
    float rs = 1.0f / stot;
    int p = p0 + pt * 16 + l15;
    bool vv = p < P_DIM;
#pragma unroll
    for (int r = 0; r < 4; ++r) {
      float a = lg[pt][r] * rs;
      if (vv) asr[r] += a;
      if (p < P_PAD) {
        int k = wave * 16 + lhi * 4 + r;
        a2b[(size_t)k * P_PAD + p] = vv ? f2bf(a * linv[pt]) : (ushort)0;
      }
    }
  }
#pragma unroll
  for (int r = 0; r < 4; ++r) {
    float v = asr[r];
    v += __shfl_xor(v, 1); v += __shfl_xor(v, 2);
    v += __shfl_xor(v, 4); v += __shfl_xor(v, 8);
    if (l15 == 0) {
      int k = wave * 16 + lhi * 4 + r;
      asum_part[((size_t)n * K_DIM + k) * PTILES + bpt] = v;
    }
  }
}

// ---------------------------------------------------------------------------
// Kernel B: agg[n,k,c] = sum_p a2[k,p]*x[c,p] via MFMA (x L3-hot after T).
// Fused epilogue: out = acc - asum*centroid.
// ---------------------------------------------------------------------------
__global__ __launch_bounds__(256, 4) void netvlad_agg(
    const float* __restrict__ x, const ushort* __restrict__ a2,
    const float* __restrict__ asum_part, const float* __restrict__ cent,
    float* __restrict__ out)
{
  const int n = blockIdx.y, ct = blockIdx.x, c0 = ct * 64;
  const int tid = threadIdx.x, wave = tid >> 6, lane = tid & 63;
  const int l15 = lane & 15, lhi = lane >> 4;

  __shared__ float asum_s[64];
  if (tid < 64) {
    const float* ap = asum_part + ((size_t)n * K_DIM + tid) * PTILES;
    float s = 0.f;
#pragma unroll
    for (int j = 0; j < PTILES; ++j) s += ap[j];
    asum_s[tid] = s;
  }
  __syncthreads();

  f32x4 acc[4];
#pragma unroll
  for (int mt = 0; mt < 4; ++mt) acc[mt] = (f32x4){0.f, 0.f, 0.f, 0.f};

  const float*  xrow = x + (size_t)n * C_DIM * P_DIM
                         + (size_t)(c0 + wave * 16 + l15) * P_DIM;
  const ushort* ab   = a2 + (size_t)n * K_DIM * P_PAD;

  for (int ks = 0; ks < 29; ++ks) {
    int pb = ks * 32 + lhi * 8;
    short8 bfrag;
    if (pb + 8 <= P_DIM) {
      f32x4 f0 = *(const f32x4*)(xrow + pb);
      f32x4 f1 = *(const f32x4*)(xrow + pb + 4);
      u32x4 up;
      up[0] = pk2(f0[0], f0[1]); up[1] = pk2(f0[2], f0[3]);
      up[2] = pk2(f1[0], f1[1]); up[3] = pk2(f1[2], f1[3]);
      bfrag = __builtin_bit_cast(short8, up);
    } else {
#pragma unroll
      for (int j = 0; j < 8; ++j)
        bfrag[j] = (pb + j < P_DIM) ? (short)f2bf(xrow[pb + j]) : (short)0;
    }
#pragma unroll
    for (int mt = 0; mt < 4; ++mt) {
      short8 afrag = *(const short8*)(ab + (size_t)(mt * 16 + l15) * P_PAD
                                         + ks * 32 + lhi * 8);
      acc[mt] = __builtin_amdgcn_mfma_f32_16x16x32_bf16(afrag, bfrag, acc[mt], 0, 0, 0);
    }
  }

  const int c = c0 + wave * 16 + l15;
#pragma unroll
  for (int mt = 0; mt < 4; ++mt) {
#pragma unroll
    for (int r = 0; r < 4; ++r) {
      int k = mt * 16 + lhi * 4 + r;
      out[((size_t)n * K_DIM + k) * C_DIM + c] =
          acc[mt][r] - asum_s[k] * cent[(size_t)k * C_DIM + c];
    }
  }
}

extern "C" void kernel_launch(void* const* d_in, const int* in_sizes, int n_in,
                              void* d_out, int out_size, void* d_ws, size_t ws_size,
                              hipStream_t stream) {
  const float* x    = (const float*)d_in[0];
  const float* w    = (const float*)d_in[1];
  const float* cent = (const float*)d_in[2];
  float* out = (float*)d_out;

  char* wsb = (char*)d_ws;
  ushort* a2        = (ushort*)wsb;
  float*  asum_part = (float*)(wsb + A2_ELEMS * sizeof(ushort));
  float*  ssq_part  = asum_part + ASUM_ELEMS;
  ushort* xtf       = (ushort*)((char*)(ssq_part + SSQ_ELEMS));

  transpose_x   <<<dim3(8, N_DIM),      256, 0, stream>>>(x, xtf, ssq_part);
  netvlad_assign<<<dim3(PTILES, N_DIM), 256, 0, stream>>>(w, xtf, ssq_part, a2, asum_part);
  netvlad_agg   <<<dim3(8, N_DIM),      256, 0, stream>>>(x, a2, asum_part, cent, out);
}

// Round 24
// 93.126 us; speedup vs baseline: 1.0458x; 1.0458x over previous
//
#include <hip/hip_runtime.h>
#include <math.h>

#define N_DIM 64
#define C_DIM 512
#define K_DIM 64
#define P_DIM 900
#define P_PAD 928          // a2 padded pixels (29*32)
#define PTILES 15          // 64-px tiles

typedef __attribute__((ext_vector_type(8))) short short8;   // 8 bf16 = 4 VGPR
typedef __attribute__((ext_vector_type(4))) float f32x4;
typedef __attribute__((ext_vector_type(4))) uint  u32x4;

#define A2_ELEMS   ((size_t)N_DIM * K_DIM * P_PAD)
#define ASUM_ELEMS ((size_t)N_DIM * K_DIM * PTILES)
#define XTF_ELEMS  ((size_t)N_DIM * PTILES * 16 * 4 * 512)   // 63 MB bf16

// fp32 -> bf16 bits, round-to-nearest-even (inputs finite)
__device__ inline ushort f2bf(float f) {
  uint u = __builtin_bit_cast(uint, f);
  u += 0x7FFFu + ((u >> 16) & 1u);
  return (ushort)(u >> 16);
}
__device__ inline uint pk2(float a, float b) {
  return (uint)f2bf(a) | ((uint)f2bf(b) << 16);
}
__device__ __forceinline__ void gload16(const float* g, float* lds_base) {
  __builtin_amdgcn_global_load_lds(
      (const __attribute__((address_space(1))) void*)g,
      (__attribute__((address_space(3))) void*)lds_base, 16, 0, 0);
}

// ---------------------------------------------------------------------------
// Kernel T (v3): STREAMING transpose, m13-shaped. Round-20's T was 2 blk/CU
// with 8 barrier-paced 32KB quanta -> 2.8 TB/s; fillBuffer does 7 TB/s with
// huge-grid zero-sync streaming. v3: block = (n, 8c octet) -> 4096 blocks
// (~5/CU by 32KB LDS), ONE stage (8 contiguous-1KB gload16/wave, rows read
// fully sequentially), ONE barrier, one write pass. Block-level overlap
// replaces the iteration pipeline. ssq dropped (computed in assign from bf16).
// xtf layout (round-20-validated): panel[((n*15+pt)*16+ks)*4+lhi][64 px][8 c].
// ---------------------------------------------------------------------------
__global__ __launch_bounds__(256, 4) void transpose_x(
    const float* __restrict__ x, ushort* __restrict__ xtf)
{
  const int oct = blockIdx.x, n = blockIdx.y;
  const int tid = threadIdx.x, wv = tid >> 6, lane = tid & 63;
  __shared__ float lds[8][1024];

  const float* xb = x + ((size_t)n * C_DIM + oct * 8) * P_DIM;
  // 32 segments: j = wv*8+i -> c-row r=j>>2, px-quarter q=j&3 (q3 = 644..899)
#pragma unroll
  for (int i = 0; i < 8; ++i) {
    int j = wv * 8 + i;
    int r = j >> 2, q = j & 3;
    int pxb = (q == 3) ? 644 : q * 256;
    gload16(xb + (size_t)r * P_DIM + pxb + lane * 4, &lds[r][pxb]);
  }
  __syncthreads();    // single drain per block; siblings stream meanwhile

  const int ks = oct >> 2, lhi = oct & 3;
#pragma unroll
  for (int j = 0; j < 4; ++j) {
    int px = j * 256 + tid;              // 0..1023
    float v[8];
#pragma unroll
    for (int c = 0; c < 8; ++c) v[c] = (px < P_DIM) ? lds[c][px] : 0.f;
    if (px < PTILES * 64) {              // < 960
      int pt = px >> 6, pxl = px & 63;
      u32x4 wvr;
      wvr[0] = pk2(v[0], v[1]); wvr[1] = pk2(v[2], v[3]);
      wvr[2] = pk2(v[4], v[5]); wvr[3] = pk2(v[6], v[7]);
      *(u32x4*)(xtf + ((((size_t)(n * PTILES + pt) * 16 + ks) * 4 + lhi) * 64
                       + pxl) * 8) = wvr;
    }
  }
}

// ---------------------------------------------------------------------------
// Kernel A (v13): logits GEMM from xtf (L3-hot, fragment-ordered) + softmax.
// Inner loop = short8 load + MFMA + in-loop bf16 ssq (AND/SHL/FMA on the
// fragment words; error ~1.7e-4 on invn -- negligible). invn via shfl_xor.
// ks loop fully unrolled (rule #20: wfrag runtime index -> scratch).
// ---------------------------------------------------------------------------
__global__ __launch_bounds__(256, 2) void netvlad_assign(
    const float* __restrict__ w, const ushort* __restrict__ xtf,
    ushort* __restrict__ a2, float* __restrict__ asum_part)
{
  const int n = blockIdx.y, bpt = blockIdx.x, p0 = bpt * 64;
  const int tid = threadIdx.x, wave = tid >> 6, lane = tid & 63;
  const int l15 = lane & 15, lhi = lane >> 4;

  __shared__ float wredm[4][4][16];
  __shared__ float wreds[4][4][16];

  short8 wfrag[16];
  const float* wrow = w + (size_t)(wave * 16 + l15) * C_DIM + lhi * 8;
#pragma unroll
  for (int ks = 0; ks < 16; ++ks) {
    f32x4 f0 = *(const f32x4*)(wrow + ks * 32);
    f32x4 f1 = *(const f32x4*)(wrow + ks * 32 + 4);
    u32x4 up;
    up[0] = pk2(f0[0], f0[1]); up[1] = pk2(f0[2], f0[3]);
    up[2] = pk2(f1[0], f1[1]); up[3] = pk2(f1[2], f1[3]);
    wfrag[ks] = __builtin_bit_cast(short8, up);
  }

  const ushort* xf_base = xtf + ((size_t)(n * PTILES + bpt) * 16) * 4 * 512;
  f32x4 acc[4];
#pragma unroll
  for (int pt = 0; pt < 4; ++pt) acc[pt] = (f32x4){0.f, 0.f, 0.f, 0.f};
  float ssqp[4] = {0.f, 0.f, 0.f, 0.f};

#pragma unroll
  for (int ks = 0; ks < 16; ++ks) {
#pragma unroll
    for (int pt = 0; pt < 4; ++pt) {
      short8 xf = *(const short8*)(xf_base + ((size_t)ks * 4 + lhi) * 512
                                          + (pt * 16 + l15) * 8);
      u32x4 uw = __builtin_bit_cast(u32x4, xf);
#pragma unroll
      for (int wd = 0; wd < 4; ++wd) {
        float lo = __builtin_bit_cast(float, uw[wd] << 16);
        float hi = __builtin_bit_cast(float, uw[wd] & 0xffff0000u);
        ssqp[pt] += lo * lo + hi * hi;
      }
      acc[pt] = __builtin_amdgcn_mfma_f32_16x16x32_bf16(wfrag[ks], xf, acc[pt], 0, 0, 0);
    }
  }

  // invn per pixel: lane holds 128 of 512 c -> reduce over lhi octet-groups
  float linv[4];
#pragma unroll
  for (int pt = 0; pt < 4; ++pt) {
    float s = ssqp[pt];
    s += __shfl_xor(s, 16);
    s += __shfl_xor(s, 32);
    linv[pt] = 1.0f / fmaxf(sqrtf(s), 1e-12f);
  }

  float lg[4][4];
#pragma unroll
  for (int pt = 0; pt < 4; ++pt) {
    float m = -1e30f;
#pragma unroll
    for (int r = 0; r < 4; ++r) { lg[pt][r] = acc[pt][r] * linv[pt]; m = fmaxf(m, lg[pt][r]); }
    m = fmaxf(m, __shfl_xor(m, 16));
    m = fmaxf(m, __shfl_xor(m, 32));
    if (lhi == 0) wredm[wave][pt][l15] = m;
  }
  __syncthreads();
#pragma unroll
  for (int pt = 0; pt < 4; ++pt) {
    float m = fmaxf(fmaxf(wredm[0][pt][l15], wredm[1][pt][l15]),
                    fmaxf(wredm[2][pt][l15], wredm[3][pt][l15]));
    float s = 0.f;
#pragma unroll
    for (int r = 0; r < 4; ++r) { lg[pt][r] = __expf(lg[pt][r] - m); s += lg[pt][r]; }
    s += __shfl_xor(s, 16);
    s += __shfl_xor(s, 32);
    if (lhi == 0) wreds[wave][pt][l15] = s;
  }
  __syncthreads();

  ushort* a2b = a2 + (size_t)n * K_DIM * P_PAD;
  float asr[4] = {0.f, 0.f, 0.f, 0.f};
#pragma unroll
  for (int pt = 0; pt < 4; ++pt) {
    float stot = wreds[0][pt][l15] + wreds[1][pt][l15] +
                 wreds[2][pt][l15] + wreds[3][pt][l15];
    float rs = 1.0f / stot;
    int p = p0 + pt * 16 + l15;
    bool vv = p < P_DIM;
#pragma unroll
    for (int r = 0; r < 4; ++r) {
      float a = lg[pt][r] * rs;
      if (vv) asr[r] += a;
      if (p < P_PAD) {
        int k = wave * 16 + lhi * 4 + r;
        a2b[(size_t)k * P_PAD + p] = vv ? f2bf(a * linv[pt]) : (ushort)0;
      }
    }
  }
#pragma unroll
  for (int r = 0; r < 4; ++r) {
    float v = asr[r];
    v += __shfl_xor(v, 1); v += __shfl_xor(v, 2);
    v += __shfl_xor(v, 4); v += __shfl_xor(v, 8);
    if (l15 == 0) {
      int k = wave * 16 + lhi * 4 + r;
      asum_part[((size_t)n * K_DIM + k) * PTILES + bpt] = v;
    }
  }
}

// ---------------------------------------------------------------------------
// Kernel B: agg[n,k,c] = sum_p a2[k,p]*x[c,p] via MFMA (x L3-hot after T).
// Fused epilogue: out = acc - asum*centroid.
// ---------------------------------------------------------------------------
__global__ __launch_bounds__(256, 4) void netvlad_agg(
    const float* __restrict__ x, const ushort* __restrict__ a2,
    const float* __restrict__ asum_part, const float* __restrict__ cent,
    float* __restrict__ out)
{
  const int n = blockIdx.y, ct = blockIdx.x, c0 = ct * 64;
  const int tid = threadIdx.x, wave = tid >> 6, lane = tid & 63;
  const int l15 = lane & 15, lhi = lane >> 4;

  __shared__ float asum_s[64];
  if (tid < 64) {
    const float* ap = asum_part + ((size_t)n * K_DIM + tid) * PTILES;
    float s = 0.f;
#pragma unroll
    for (int j = 0; j < PTILES; ++j) s += ap[j];
    asum_s[tid] = s;
  }
  __syncthreads();

  f32x4 acc[4];
#pragma unroll
  for (int mt = 0; mt < 4; ++mt) acc[mt] = (f32x4){0.f, 0.f, 0.f, 0.f};

  const float*  xrow = x + (size_t)n * C_DIM * P_DIM
                         + (size_t)(c0 + wave * 16 + l15) * P_DIM;
  const ushort* ab   = a2 + (size_t)n * K_DIM * P_PAD;

  for (int ks = 0; ks < 29; ++ks) {
    int pb = ks * 32 + lhi * 8;
    short8 bfrag;
    if (pb + 8 <= P_DIM) {
      f32x4 f0 = *(const f32x4*)(xrow + pb);
      f32x4 f1 = *(const f32x4*)(xrow + pb + 4);
      u32x4 up;
      up[0] = pk2(f0[0], f0[1]); up[1] = pk2(f0[2], f0[3]);
      up[2] = pk2(f1[0], f1[1]); up[3] = pk2(f1[2], f1[3]);
      bfrag = __builtin_bit_cast(short8, up);
    } else {
#pragma unroll
      for (int j = 0; j < 8; ++j)
        bfrag[j] = (pb + j < P_DIM) ? (short)f2bf(xrow[pb + j]) : (short)0;
    }
#pragma unroll
    for (int mt = 0; mt < 4; ++mt) {
      short8 afrag = *(const short8*)(ab + (size_t)(mt * 16 + l15) * P_PAD
                                         + ks * 32 + lhi * 8);
      acc[mt] = __builtin_amdgcn_mfma_f32_16x16x32_bf16(afrag, bfrag, acc[mt], 0, 0, 0);
    }
  }

  const int c = c0 + wave * 16 + l15;
#pragma unroll
  for (int mt = 0; mt < 4; ++mt) {
#pragma unroll
    for (int r = 0; r < 4; ++r) {
      int k = mt * 16 + lhi * 4 + r;
      out[((size_t)n * K_DIM + k) * C_DIM + c] =
          acc[mt][r] - asum_s[k] * cent[(size_t)k * C_DIM + c];
    }
  }
}

extern "C" void kernel_launch(void* const* d_in, const int* in_sizes, int n_in,
                              void* d_out, int out_size, void* d_ws, size_t ws_size,
                              hipStream_t stream) {
  const float* x    = (const float*)d_in[0];
  const float* w    = (const float*)d_in[1];
  const float* cent = (const float*)d_in[2];
  float* out = (float*)d_out;

  char* wsb = (char*)d_ws;
  ushort* a2        = (ushort*)wsb;
  float*  asum_part = (float*)(wsb + A2_ELEMS * sizeof(ushort));
  ushort* xtf       = (ushort*)((char*)(asum_part + ASUM_ELEMS));

  transpose_x   <<<dim3(64, N_DIM),     256, 0, stream>>>(x, xtf);
  netvlad_assign<<<dim3(PTILES, N_DIM), 256, 0, stream>>>(w, xtf, a2, asum_part);
  netvlad_agg   <<<dim3(8, N_DIM),      256, 0, stream>>>(x, a2, asum_part, cent, out);
}